// Round 1
// baseline (291.866 us; speedup 1.0000x reference)
//
#include <hip/hip_runtime.h>

// ---------------------------------------------------------------------------
// CrossAttention (B=1, N=4096, H=8, DH=64, DQ=320, DC=768, L=77, C=4)
// fp32 everywhere (threshold 1.95e-3; no fp32 MFMA on CDNA4 -> vector ALU).
// Pipeline: q = x@Wq (head-split) ; K/V = ctx@Wk/Wv (K-split partials + reduce)
//           max(sim_c0) -> atomicMax ; fused attention (QK^T, softmax, PV)
//           out = att@Wo + bo
// ---------------------------------------------------------------------------

#define L77 77
#define DCV 768

// ws offsets in floats
#define Q_OFF   0ull          // 16*4096*64      = 4,194,304
#define K_OFF   4194304ull    // 5*8*77*64       =   197,120
#define V_OFF   4391424ull    //                 =   197,120
#define ATT_OFF 4588544ull    // 2*4096*512      = 4,194,304
#define P_OFF   8782848ull    // 8*10*77*512     = 3,153,920
#define MAX_OFF 11936768ull   // 1 uint

__device__ __forceinline__ unsigned enc_f(float f) {
  int b = __float_as_int(f);
  return (b >= 0) ? ((unsigned)b | 0x80000000u) : ~(unsigned)b;
}
__device__ __forceinline__ float dec_f(unsigned u) {
  unsigned b = (u & 0x80000000u) ? (u ^ 0x80000000u) : ~u;
  return __int_as_float((int)b);
}

#define FMA16(ACC, A, B)                                                                   \
  ACC[0][0] += A.x*B.x; ACC[0][1] += A.x*B.y; ACC[0][2] += A.x*B.z; ACC[0][3] += A.x*B.w;  \
  ACC[1][0] += A.y*B.x; ACC[1][1] += A.y*B.y; ACC[1][2] += A.y*B.z; ACC[1][3] += A.y*B.w;  \
  ACC[2][0] += A.z*B.x; ACC[2][1] += A.z*B.y; ACC[2][2] += A.z*B.z; ACC[2][3] += A.z*B.w;  \
  ACC[3][0] += A.w*B.x; ACC[3][1] += A.w*B.y; ACC[3][2] += A.w*B.z; ACC[3][3] += A.w*B.w;

__global__ void k_init(unsigned* maxslot) { *maxslot = 0u; }

// ---------------------------------------------------------------------------
// q = x @ Wq, head-split output: q[(b*8+h)*4096 + i][64]
// grid (128, 8): 64-row tile x one head (64 cols). 256 thr, 4x4 micro.
// ---------------------------------------------------------------------------
__global__ __launch_bounds__(256) void k_gemm_q(const float* __restrict__ x,
                                                const float* __restrict__ Wq,
                                                float* __restrict__ q) {
  __shared__ float As[32][64];  // [k][m]
  __shared__ float Bs[32][64];  // [k][n]
  const int tid = threadIdx.x;
  const int mb = blockIdx.x * 64;
  const int h  = blockIdx.y;
  const int ty = tid >> 4, tx = tid & 15;
  const int m0 = ty * 4, n0 = tx * 4;
  const int lm = tid & 63;
  const int lk = (tid >> 6) * 8;
  float acc[4][4] = {};
  for (int k0 = 0; k0 < 320; k0 += 32) {
    const float* xp = x + (size_t)(mb + lm) * 320 + k0 + lk;
    float4 a0 = *reinterpret_cast<const float4*>(xp);
    float4 a1 = *reinterpret_cast<const float4*>(xp + 4);
    As[lk + 0][lm] = a0.x; As[lk + 1][lm] = a0.y;
    As[lk + 2][lm] = a0.z; As[lk + 3][lm] = a0.w;
    As[lk + 4][lm] = a1.x; As[lk + 5][lm] = a1.y;
    As[lk + 6][lm] = a1.z; As[lk + 7][lm] = a1.w;
#pragma unroll
    for (int r = 0; r < 2; ++r) {
      int idx = tid + r * 256;
      int bk = idx >> 4, bn = (idx & 15) * 4;
      *reinterpret_cast<float4*>(&Bs[bk][bn]) =
          *reinterpret_cast<const float4*>(Wq + (size_t)(k0 + bk) * 512 + h * 64 + bn);
    }
    __syncthreads();
#pragma unroll
    for (int kk = 0; kk < 32; ++kk) {
      float4 a = *reinterpret_cast<const float4*>(&As[kk][m0]);
      float4 b = *reinterpret_cast<const float4*>(&Bs[kk][n0]);
      FMA16(acc, a, b)
    }
    __syncthreads();
  }
  const int row = mb + m0;
  const int bb = row >> 12;  // batch (0/1)
#pragma unroll
  for (int i = 0; i < 4; ++i) {
    int ii = (row + i) & 4095;
    float4 v = make_float4(acc[i][0], acc[i][1], acc[i][2], acc[i][3]);
    *reinterpret_cast<float4*>(q + ((size_t)((bb * 8 + h) * 4096 + ii)) * 64 + n0) = v;
  }
}

// ---------------------------------------------------------------------------
// ctx K/V projections, K-split into 8 partials.
// grid (4 ntile128, 5 ctx, 16 = kv*8+ks). 256 thr, 5x8 micro, 77 rows.
// pbuf[ks][ctx*2+kv][77][512]
// ---------------------------------------------------------------------------
__global__ __launch_bounds__(256) void k_gemm_ctx(const float* __restrict__ uc,
                                                  const float* __restrict__ ck,
                                                  const float* __restrict__ cv,
                                                  const float* __restrict__ Wk,
                                                  const float* __restrict__ Wv,
                                                  float* __restrict__ pbuf) {
  __shared__ float CT[32][80];    // [k][row] transposed ctx tile
  __shared__ float Wsh[32][128];  // [k][col]
  const int tid = threadIdx.x;
  const int colbase = blockIdx.x * 128;
  const int ctx = blockIdx.y;
  const int kv = blockIdx.z >> 3;
  const int ks = blockIdx.z & 7;
  const float* csrc = (ctx == 0) ? uc : ((kv ? cv : ck) + (size_t)(ctx - 1) * L77 * DCV);
  const float* wsrc = kv ? Wv : Wk;
  const int ty = tid >> 4, tx = tid & 15;
  float acc[5][8] = {};
  for (int cc = 0; cc < 3; ++cc) {
    int kc0 = ks * 96 + cc * 32;
    for (int idx = tid; idx < 616; idx += 256) {  // 77 rows x 8 float4
      int rrow = idx >> 3, kq = (idx & 7) * 4;
      float4 v = *reinterpret_cast<const float4*>(csrc + (size_t)rrow * DCV + kc0 + kq);
      CT[kq + 0][rrow] = v.x; CT[kq + 1][rrow] = v.y;
      CT[kq + 2][rrow] = v.z; CT[kq + 3][rrow] = v.w;
    }
#pragma unroll
    for (int r = 0; r < 4; ++r) {
      int idx = tid + r * 256;
      int kk = idx >> 5, c4 = (idx & 31) * 4;
      *reinterpret_cast<float4*>(&Wsh[kk][c4]) =
          *reinterpret_cast<const float4*>(wsrc + (size_t)(kc0 + kk) * 512 + colbase + c4);
    }
    __syncthreads();
#pragma unroll
    for (int kk = 0; kk < 32; ++kk) {
      float a[5];
#pragma unroll
      for (int r = 0; r < 5; ++r) a[r] = CT[kk][ty + 16 * r];
      float4 b0 = *reinterpret_cast<const float4*>(&Wsh[kk][tx * 8]);
      float4 b1 = *reinterpret_cast<const float4*>(&Wsh[kk][tx * 8 + 4]);
      float b[8] = {b0.x, b0.y, b0.z, b0.w, b1.x, b1.y, b1.z, b1.w};
#pragma unroll
      for (int r = 0; r < 5; ++r)
#pragma unroll
        for (int c = 0; c < 8; ++c) acc[r][c] += a[r] * b[c];
    }
    __syncthreads();
  }
  size_t pb = (size_t)(ks * 10 + ctx * 2 + kv) * L77 * 512;
#pragma unroll
  for (int r = 0; r < 5; ++r) {
    int rrow = ty + 16 * r;
    if (rrow < L77) {
      float* dst = pbuf + pb + (size_t)rrow * 512 + colbase + tx * 8;
      *reinterpret_cast<float4*>(dst) = make_float4(acc[r][0], acc[r][1], acc[r][2], acc[r][3]);
      *reinterpret_cast<float4*>(dst + 4) = make_float4(acc[r][4], acc[r][5], acc[r][6], acc[r][7]);
    }
  }
}

// reduce 8 K-split partials -> kbuf/vbuf[(ctx*8+h)*77 + j][64]
__global__ __launch_bounds__(256) void k_reduce_ctx(const float* __restrict__ pbuf,
                                                    float* __restrict__ kbuf,
                                                    float* __restrict__ vbuf) {
  int o = blockIdx.x * 256 + threadIdx.x;  // < 10*77*512 = 394240
  int c = o & 511;
  int rest = o >> 9;
  int j = rest % L77;
  int ctxkv = rest / L77;
  float s = 0.f;
#pragma unroll
  for (int ks = 0; ks < 8; ++ks)
    s += pbuf[((size_t)(ks * 10 + ctxkv) * L77 + j) * 512 + c];
  int ctx = ctxkv >> 1, kv = ctxkv & 1;
  int h = c >> 6, d = c & 63;
  float* dst = kv ? vbuf : kbuf;
  dst[((size_t)(ctx * 8 + h) * L77 + j) * 64 + d] = s;
}

// ---------------------------------------------------------------------------
// global max of sim_c[0] (scaled). grid (64 rowtiles, 8 heads).
// ---------------------------------------------------------------------------
__global__ __launch_bounds__(256) void k_max(const float* __restrict__ q,
                                             const float* __restrict__ kbuf,
                                             unsigned* __restrict__ maxslot) {
  __shared__ float qT[64][68];
  __shared__ float KT[64][80];
  __shared__ float red[256];
  const int tid = threadIdx.x;
  const int rowbase = blockIdx.x * 64;
  const int h = blockIdx.y;
  const int bh = 8 + h;  // q_c
#pragma unroll
  for (int r = 0; r < 4; ++r) {
    int idx = tid + r * 256;
    int m = idx >> 4, d4 = (idx & 15) * 4;
    float4 v = *reinterpret_cast<const float4*>(q + ((size_t)bh * 4096 + rowbase + m) * 64 + d4);
    qT[d4 + 0][m] = v.x; qT[d4 + 1][m] = v.y; qT[d4 + 2][m] = v.z; qT[d4 + 3][m] = v.w;
  }
  const float* kc = kbuf + (size_t)(1 * 8 + h) * L77 * 64;  // ctx=1 (c0)
  for (int idx = tid; idx < 1232; idx += 256) {
    int j = idx >> 4, d4 = (idx & 15) * 4;
    float4 v = *reinterpret_cast<const float4*>(kc + (size_t)j * 64 + d4);
    KT[d4 + 0][j] = v.x; KT[d4 + 1][j] = v.y; KT[d4 + 2][j] = v.z; KT[d4 + 3][j] = v.w;
  }
  __syncthreads();
  const int ty = tid >> 4, tx = tid & 15;
  const int m0 = ty * 4;
  float lmax = -3.4e38f;
#pragma unroll
  for (int jt = 0; jt < 2; ++jt) {
    if (jt == 1 && tx >= 4) continue;
    int j0 = jt * 64 + tx * 4;
    float acc1[4][4] = {};
    for (int k = 0; k < 64; ++k) {
      float4 a = *reinterpret_cast<const float4*>(&qT[k][m0]);
      float4 b = *reinterpret_cast<const float4*>(&KT[k][j0]);
      FMA16(acc1, a, b)
    }
#pragma unroll
    for (int jj = 0; jj < 4; ++jj) {
      if (j0 + jj < L77) {
#pragma unroll
        for (int i2 = 0; i2 < 4; ++i2) lmax = fmaxf(lmax, acc1[i2][jj] * 0.125f);
      }
    }
  }
  red[tid] = lmax;
  __syncthreads();
  for (int s = 128; s > 0; s >>= 1) {
    if (tid < s) red[tid] = fmaxf(red[tid], red[tid + s]);
    __syncthreads();
  }
  if (tid == 0) atomicMax(maxslot, enc_f(red[0]));
}

// ---------------------------------------------------------------------------
// fused attention. grid (64 rowtiles, 8 heads, 2 parts: 0=uc, 1=c-group)
// per ctx: QK^T (4x4 micro) -> exp (no max-sub, sims ~ [-2,2]) -> PV -> 1/sum
// ---------------------------------------------------------------------------
__global__ __launch_bounds__(256) void k_attn(const float* __restrict__ q,
                                              const float* __restrict__ kbuf,
                                              const float* __restrict__ vbuf,
                                              const float* __restrict__ extra,
                                              const int* __restrict__ tptr,
                                              const unsigned* __restrict__ maxslot,
                                              float* __restrict__ att) {
  __shared__ float qT[64][68];    // [d][m]
  __shared__ float kvs[64 * 80];  // KT [d][j] stride 80  |  V [j][d] stride 64
  __shared__ float PT[80][68];    // [j][m]
  __shared__ float sums[4][64];
  const int tid = threadIdx.x;
  const int rowbase = blockIdx.x * 64;
  const int h = blockIdx.y;
  const int part = blockIdx.z;
  const int bh = part ? (8 + h) : h;
  const int ty = tid >> 4, tx = tid & 15;
  const int m0 = ty * 4, n0 = tx * 4;
  const int em = tid & 63, jg = tid >> 6;

#pragma unroll
  for (int r = 0; r < 4; ++r) {
    int idx = tid + r * 256;
    int m = idx >> 4, d4 = (idx & 15) * 4;
    float4 v = *reinterpret_cast<const float4*>(q + ((size_t)bh * 4096 + rowbase + m) * 64 + d4);
    qT[d4 + 0][m] = v.x; qT[d4 + 1][m] = v.y; qT[d4 + 2][m] = v.z; qT[d4 + 3][m] = v.w;
  }
  const float weight = ((float)(*tptr)) * (4.6f / 50.0f);
  const float wmask = weight * dec_f(*maxslot);  // W_DOT = 1
  float acc[4][4] = {};
  const int nctx = part ? 4 : 1;
  for (int ci = 0; ci < nctx; ++ci) {
    const int ctx = part ? (1 + ci) : 0;
    __syncthreads();  // prev V / prev PT / qT ready
    const float* kc = kbuf + (size_t)(ctx * 8 + h) * L77 * 64;
    for (int idx = tid; idx < 1232; idx += 256) {
      int j = idx >> 4, d4 = (idx & 15) * 4;
      float4 v = *reinterpret_cast<const float4*>(kc + (size_t)j * 64 + d4);
      kvs[(d4 + 0) * 80 + j] = v.x; kvs[(d4 + 1) * 80 + j] = v.y;
      kvs[(d4 + 2) * 80 + j] = v.z; kvs[(d4 + 3) * 80 + j] = v.w;
    }
    __syncthreads();
    // --- GEMM1: sim = q @ k^T * scale ---
#pragma unroll
    for (int jt = 0; jt < 2; ++jt) {
      if (jt == 1 && tx >= 4) continue;
      int j0 = jt * 64 + tx * 4;
      float acc1[4][4] = {};
      for (int k = 0; k < 64; ++k) {
        float4 a = *reinterpret_cast<const float4*>(&qT[k][m0]);
        float4 b = *reinterpret_cast<const float4*>(&kvs[k * 80 + j0]);
        FMA16(acc1, a, b)
      }
#pragma unroll
      for (int jj = 0; jj < 4; ++jj) {
        int j = j0 + jj;
        if (j < L77) {
#pragma unroll
          for (int i2 = 0; i2 < 4; ++i2) PT[j][m0 + i2] = acc1[i2][jj] * 0.125f;
        }
      }
    }
    __syncthreads();
    // --- stage V (overwrites KT) + exp pass on PT ---
    const float* vc = vbuf + (size_t)(ctx * 8 + h) * L77 * 64;
    for (int idx = tid; idx < 1232; idx += 256) {
      int j = idx >> 4, d4 = (idx & 15) * 4;
      *reinterpret_cast<float4*>(&kvs[j * 64 + d4]) =
          *reinterpret_cast<const float4*>(vc + (size_t)j * 64 + d4);
    }
    {
      float psum = 0.f;
      const bool isc0 = (part == 1) && (ci == 0);
      const float* exrow = extra + ((size_t)h * 4096 + rowbase + em) * L77;
#pragma unroll
      for (int jj = 0; jj < 20; ++jj) {
        int j = jg * 20 + jj;
        if (j < L77) {
          float val = PT[j][em];
          if (isc0) val += wmask * exrow[j];
          float e = expf(val);
          PT[j][em] = e;
          psum += e;
        }
      }
      sums[jg][em] = psum;
    }
    __syncthreads();
    // --- GEMM2: out = P @ V ---
    float acc2[4][4] = {};
    for (int j = 0; j < L77; ++j) {
      float4 a = *reinterpret_cast<const float4*>(&PT[j][m0]);
      float4 b = *reinterpret_cast<const float4*>(&kvs[j * 64 + n0]);
      FMA16(acc2, a, b)
    }
    float rs[4];
#pragma unroll
    for (int i2 = 0; i2 < 4; ++i2)
      rs[i2] = sums[0][m0 + i2] + sums[1][m0 + i2] + sums[2][m0 + i2] + sums[3][m0 + i2];
    if (part == 0) {
#pragma unroll
      for (int i2 = 0; i2 < 4; ++i2) {
        float inv = 1.0f / rs[i2];
        float4 v = make_float4(acc2[i2][0] * inv, acc2[i2][1] * inv,
                               acc2[i2][2] * inv, acc2[i2][3] * inv);
        *reinterpret_cast<float4*>(att + ((size_t)(rowbase + m0 + i2)) * 512 + h * 64 + n0) = v;
      }
    } else {
#pragma unroll
      for (int i2 = 0; i2 < 4; ++i2) {
        float inv = 1.0f / rs[i2];
#pragma unroll
        for (int jj = 0; jj < 4; ++jj) acc[i2][jj] += acc2[i2][jj] * inv;
      }
    }
  }
  if (part == 1) {
#pragma unroll
    for (int i2 = 0; i2 < 4; ++i2) {
      float4 v = make_float4(acc[i2][0] * 0.25f, acc[i2][1] * 0.25f,
                             acc[i2][2] * 0.25f, acc[i2][3] * 0.25f);
      *reinterpret_cast<float4*>(att + ((size_t)(4096 + rowbase + m0 + i2)) * 512 + h * 64 + n0) = v;
    }
  }
}

// ---------------------------------------------------------------------------
// out = att @ Wo + bo. grid (128, 5): 64x64 tiles, K=512.
// ---------------------------------------------------------------------------
__global__ __launch_bounds__(256) void k_gemm_out(const float* __restrict__ A,
                                                  const float* __restrict__ Wo,
                                                  const float* __restrict__ bo,
                                                  float* __restrict__ out) {
  __shared__ float As[32][64];
  __shared__ float Bs[32][64];
  const int tid = threadIdx.x;
  const int mb = blockIdx.x * 64;
  const int nb = blockIdx.y * 64;
  const int ty = tid >> 4, tx = tid & 15;
  const int m0 = ty * 4, n0 = tx * 4;
  const int lm = tid & 63;
  const int lk = (tid >> 6) * 8;
  float acc[4][4] = {};
  for (int k0 = 0; k0 < 512; k0 += 32) {
    const float* ap = A + (size_t)(mb + lm) * 512 + k0 + lk;
    float4 a0 = *reinterpret_cast<const float4*>(ap);
    float4 a1 = *reinterpret_cast<const float4*>(ap + 4);
    As[lk + 0][lm] = a0.x; As[lk + 1][lm] = a0.y;
    As[lk + 2][lm] = a0.z; As[lk + 3][lm] = a0.w;
    As[lk + 4][lm] = a1.x; As[lk + 5][lm] = a1.y;
    As[lk + 6][lm] = a1.z; As[lk + 7][lm] = a1.w;
#pragma unroll
    for (int r = 0; r < 2; ++r) {
      int idx = tid + r * 256;
      int bk = idx >> 4, bn = (idx & 15) * 4;
      *reinterpret_cast<float4*>(&Bs[bk][bn]) =
          *reinterpret_cast<const float4*>(Wo + (size_t)(k0 + bk) * 320 + nb + bn);
    }
    __syncthreads();
#pragma unroll
    for (int kk = 0; kk < 32; ++kk) {
      float4 a = *reinterpret_cast<const float4*>(&As[kk][m0]);
      float4 b = *reinterpret_cast<const float4*>(&Bs[kk][n0]);
      FMA16(acc, a, b)
    }
    __syncthreads();
  }
  float4 bias = *reinterpret_cast<const float4*>(bo + nb + n0);
#pragma unroll
  for (int i = 0; i < 4; ++i) {
    float4 v = make_float4(acc[i][0] + bias.x, acc[i][1] + bias.y,
                           acc[i][2] + bias.z, acc[i][3] + bias.w);
    *reinterpret_cast<float4*>(out + (size_t)(mb + m0 + i) * 320 + nb + n0) = v;
  }
}

extern "C" void kernel_launch(void* const* d_in, const int* in_sizes, int n_in,
                              void* d_out, int out_size, void* d_ws, size_t ws_size,
                              hipStream_t stream) {
  (void)in_sizes; (void)n_in; (void)out_size; (void)ws_size;
  const float* x   = (const float*)d_in[0];
  const float* uc  = (const float*)d_in[1];
  const float* ck  = (const float*)d_in[2];
  const float* cv  = (const float*)d_in[3];
  const float* ex  = (const float*)d_in[4];
  const float* Wq  = (const float*)d_in[5];
  const float* Wk  = (const float*)d_in[6];
  const float* Wv  = (const float*)d_in[7];
  const float* Wo  = (const float*)d_in[8];
  const float* bo  = (const float*)d_in[9];
  const int*   tp  = (const int*)d_in[10];

  float* ws   = (float*)d_ws;
  float* q    = ws + Q_OFF;
  float* kbuf = ws + K_OFF;
  float* vbuf = ws + V_OFF;
  float* att  = ws + ATT_OFF;
  float* pbuf = ws + P_OFF;
  unsigned* maxslot = (unsigned*)(ws + MAX_OFF);

  k_init<<<1, 1, 0, stream>>>(maxslot);
  k_gemm_q<<<dim3(128, 8), 256, 0, stream>>>(x, Wq, q);
  k_gemm_ctx<<<dim3(4, 5, 16), 256, 0, stream>>>(uc, ck, cv, Wk, Wv, pbuf);
  k_reduce_ctx<<<1540, 256, 0, stream>>>(pbuf, kbuf, vbuf);
  k_max<<<dim3(64, 8), 256, 0, stream>>>(q, kbuf, maxslot);
  k_attn<<<dim3(64, 8, 2), 256, 0, stream>>>(q, kbuf, vbuf, ex, tp, maxslot, att);
  k_gemm_out<<<dim3(128, 5), 256, 0, stream>>>(att, Wo, bo, (float*)d_out);
}

// Round 2
// 176.784 us; speedup vs baseline: 1.6510x; 1.6510x over previous
//
#include <hip/hip_runtime.h>

// ---------------------------------------------------------------------------
// CrossAttention (B=1, N=4096, H=8, DH=64, DQ=320, DC=768, L=77, C=4)
// bf16 MFMA (16x16x32, fp32 accum) for all GEMM stages; fp32 softmax.
// Stages: convert/transpose -> q=x@Wq -> K/V=ctx@W{k,v} -> max(sim_c0)
//         -> fused attention -> out=att@Wo+bo
// ---------------------------------------------------------------------------

typedef __attribute__((ext_vector_type(8))) short          bf16x8;
typedef __attribute__((ext_vector_type(4))) float          f32x4;
typedef __attribute__((ext_vector_type(8))) unsigned short u16x8;

// ws byte offsets (all 16B-aligned)
#define OFF_XB   0ull          // 8192*320*2      = 5,242,880
#define OFF_CTXB 5242880ull    // 9*77*768*2      = 1,064,448
#define OFF_WQT  6307840ull    // 512*320*2       =   327,680
#define OFF_WKT  6635520ull    // 512*768*2       =   786,432
#define OFF_WVT  7421952ull    // 512*768*2       =   786,432
#define OFF_WOT  8208384ull    // 320*512*2       =   327,680
#define OFF_Q    8536064ull    // 16*4096*64*2    = 8,388,608
#define OFF_K    16924672ull   // 5*8*77*64*2     =   394,240
#define OFF_VT   17318912ull   // 5*8*64*80*2     =   819,200
#define OFF_ATT  18138112ull   // 8192*512*2      = 8,388,608
#define OFF_MAX  26526720ull   // 4 bytes

__device__ __forceinline__ unsigned short bf_cvt(float f) {
  unsigned u = __float_as_uint(f);
  unsigned r = u + 0x7FFFu + ((u >> 16) & 1u);
  return (unsigned short)(r >> 16);
}
__device__ __forceinline__ unsigned enc_f(float f) {
  int b = __float_as_int(f);
  return (b >= 0) ? ((unsigned)b | 0x80000000u) : ~(unsigned)b;
}
__device__ __forceinline__ float dec_f(unsigned u) {
  unsigned b = (u & 0x80000000u) ? (u ^ 0x80000000u) : ~u;
  return __int_as_float((int)b);
}

// --- convert x + ctx to bf16 (and init maxslot) ----------------------------
__global__ __launch_bounds__(256) void k_convert(const float* __restrict__ x,
                                                 const float* __restrict__ uc,
                                                 const float* __restrict__ ck,
                                                 const float* __restrict__ cv,
                                                 unsigned short* __restrict__ xb,
                                                 unsigned short* __restrict__ ctxb,
                                                 unsigned* __restrict__ maxslot) {
  size_t idx = (size_t)blockIdx.x * 256 + threadIdx.x;
  if (idx == 0) *maxslot = 0u;
  if (idx < 655360) {  // x: 8192*320/4
    float4 v = reinterpret_cast<const float4*>(x)[idx];
    ushort4 o = {bf_cvt(v.x), bf_cvt(v.y), bf_cvt(v.z), bf_cvt(v.w)};
    reinterpret_cast<ushort4*>(xb)[idx] = o;
  } else {
    size_t r = idx - 655360;
    if (r < 133056) {  // 9*77*768/4
      const float4* s = (r < 14784) ? (reinterpret_cast<const float4*>(uc) + r)
                      : (r < 73920) ? (reinterpret_cast<const float4*>(ck) + (r - 14784))
                                    : (reinterpret_cast<const float4*>(cv) + (r - 73920));
      float4 v = *s;
      ushort4 o = {bf_cvt(v.x), bf_cvt(v.y), bf_cvt(v.z), bf_cvt(v.w)};
      reinterpret_cast<ushort4*>(ctxb)[r] = o;
    }
  }
}

// --- transpose-convert the 4 weights ---------------------------------------
__global__ __launch_bounds__(256) void k_tw(const float* __restrict__ Wq, const float* __restrict__ Wk,
                                            const float* __restrict__ Wv, const float* __restrict__ Wo,
                                            unsigned short* __restrict__ WqT, unsigned short* __restrict__ WkT,
                                            unsigned short* __restrict__ WvT, unsigned short* __restrict__ WoT) {
  __shared__ float T[32][33];
  int z = blockIdx.z;
  const float* src; unsigned short* dst; int R, C;
  if (z == 0)      { src = Wq; dst = WqT; R = 320; C = 512; }
  else if (z == 1) { src = Wk; dst = WkT; R = 768; C = 512; }
  else if (z == 2) { src = Wv; dst = WvT; R = 768; C = 512; }
  else             { src = Wo; dst = WoT; R = 512; C = 320; }
  int c0 = blockIdx.x * 32, r0 = blockIdx.y * 32;
  if (c0 >= C || r0 >= R) return;
  int t = threadIdx.x;
  {
    int r = t >> 3, c4 = (t & 7) * 4;
    float4 v = *reinterpret_cast<const float4*>(src + (size_t)(r0 + r) * C + c0 + c4);
    T[r][c4] = v.x; T[r][c4 + 1] = v.y; T[r][c4 + 2] = v.z; T[r][c4 + 3] = v.w;
  }
  __syncthreads();
  {
    int c = t >> 3, r4 = (t & 7) * 4;
    ushort4 o = {bf_cvt(T[r4][c]), bf_cvt(T[r4 + 1][c]), bf_cvt(T[r4 + 2][c]), bf_cvt(T[r4 + 3][c])};
    *reinterpret_cast<ushort4*>(dst + (size_t)(c0 + c) * R + r0 + r4) = o;
  }
}

// --- q = x @ Wq (head-split bf16 out) : M=8192 N=512 K=320 -----------------
__global__ __launch_bounds__(256) void k_gemm_q(const unsigned short* __restrict__ xb,
                                                const unsigned short* __restrict__ WqT,
                                                unsigned short* __restrict__ q) {
  __shared__ unsigned short As[128 * 40];
  __shared__ unsigned short Bs[128 * 40];
  int tid = threadIdx.x, lane = tid & 63, w = tid >> 6;
  int wr = w >> 1, wc = w & 1, l15 = lane & 15, qd = lane >> 4;
  int mb = blockIdx.x * 128, nb = blockIdx.y * 128;
  f32x4 acc[4][4] = {};
  for (int k0 = 0; k0 < 320; k0 += 32) {
    for (int u = tid; u < 512; u += 256) {
      int r = u >> 2, c8 = (u & 3) * 8;
      *reinterpret_cast<u16x8*>(&As[r * 40 + c8]) =
          *reinterpret_cast<const u16x8*>(&xb[(size_t)(mb + r) * 320 + k0 + c8]);
    }
    for (int u = tid; u < 512; u += 256) {
      int r = u >> 2, c8 = (u & 3) * 8;
      *reinterpret_cast<u16x8*>(&Bs[r * 40 + c8]) =
          *reinterpret_cast<const u16x8*>(&WqT[(size_t)(nb + r) * 320 + k0 + c8]);
    }
    __syncthreads();
    bf16x8 a[4], b[4];
#pragma unroll
    for (int mi = 0; mi < 4; ++mi)
      a[mi] = *reinterpret_cast<const bf16x8*>(&As[(wr * 64 + mi * 16 + l15) * 40 + qd * 8]);
#pragma unroll
    for (int ni = 0; ni < 4; ++ni)
      b[ni] = *reinterpret_cast<const bf16x8*>(&Bs[(wc * 64 + ni * 16 + l15) * 40 + qd * 8]);
#pragma unroll
    for (int mi = 0; mi < 4; ++mi)
#pragma unroll
      for (int ni = 0; ni < 4; ++ni)
        acc[mi][ni] = __builtin_amdgcn_mfma_f32_16x16x32_bf16(a[mi], b[ni], acc[mi][ni], 0, 0, 0);
    __syncthreads();
  }
#pragma unroll
  for (int mi = 0; mi < 4; ++mi)
#pragma unroll
    for (int ni = 0; ni < 4; ++ni)
#pragma unroll
      for (int r = 0; r < 4; ++r) {
        int m = mb + wr * 64 + mi * 16 + qd * 4 + r;
        int n = nb + wc * 64 + ni * 16 + l15;
        int b_ = m >> 12, i = m & 4095, h = n >> 6, d = n & 63;
        q[((size_t)((b_ * 8 + h) * 4096 + i)) * 64 + d] = bf_cvt(acc[mi][ni][r]);
      }
}

// --- K/V = ctx @ W{k,v} : 10 GEMMs of M=77 N=512 K=768 ---------------------
// grid (8 coltiles of 64, 10). K out row-major [ctx][h][77][64]; V out
// transposed [ctx][h][64][80].
__global__ __launch_bounds__(256) void k_gemm_ctx(const unsigned short* __restrict__ ctxb,
                                                  const unsigned short* __restrict__ WkT,
                                                  const unsigned short* __restrict__ WvT,
                                                  unsigned short* __restrict__ kb,
                                                  unsigned short* __restrict__ vt) {
  __shared__ unsigned short As[80 * 40];
  __shared__ unsigned short Bs[64 * 40];
  int tid = threadIdx.x, lane = tid & 63, w = tid >> 6;
  int l15 = lane & 15, qd = lane >> 4;
  int nb = blockIdx.x * 64;
  int g = blockIdx.y;  // 0..9
  int kv = g >= 5, cidx = g % 5;
  int src = kv ? (cidx == 0 ? 0 : 4 + cidx) : (cidx == 0 ? 0 : cidx);
  const unsigned short* WT = kv ? WvT : WkT;
  f32x4 acc[5] = {};
  for (int k0 = 0; k0 < 768; k0 += 32) {
    for (int u = tid; u < 320; u += 256) {
      int r = u >> 2, c8 = (u & 3) * 8;
      u16x8 v = {0, 0, 0, 0, 0, 0, 0, 0};
      if (r < 77) v = *reinterpret_cast<const u16x8*>(&ctxb[(size_t)(src * 77 + r) * 768 + k0 + c8]);
      *reinterpret_cast<u16x8*>(&As[r * 40 + c8]) = v;
    }
    for (int u = tid; u < 256; u += 256) {
      int r = u >> 2, c8 = (u & 3) * 8;
      *reinterpret_cast<u16x8*>(&Bs[r * 40 + c8]) =
          *reinterpret_cast<const u16x8*>(&WT[(size_t)(nb + r) * 768 + k0 + c8]);
    }
    __syncthreads();
    bf16x8 b = *reinterpret_cast<const bf16x8*>(&Bs[(w * 16 + l15) * 40 + qd * 8]);
#pragma unroll
    for (int mi = 0; mi < 5; ++mi) {
      bf16x8 a = *reinterpret_cast<const bf16x8*>(&As[(mi * 16 + l15) * 40 + qd * 8]);
      acc[mi] = __builtin_amdgcn_mfma_f32_16x16x32_bf16(a, b, acc[mi], 0, 0, 0);
    }
    __syncthreads();
  }
#pragma unroll
  for (int mi = 0; mi < 5; ++mi)
#pragma unroll
    for (int r = 0; r < 4; ++r) {
      int j = mi * 16 + qd * 4 + r;
      if (j >= 77) continue;
      int n = nb + w * 16 + l15;
      int h = n >> 6, d = n & 63;
      unsigned short val = bf_cvt(acc[mi][r]);
      if (!kv) kb[((size_t)(cidx * 8 + h) * 77 + j) * 64 + d] = val;
      else     vt[((size_t)(cidx * 8 + h) * 64 + d) * 80 + j] = val;
    }
}

// --- global max of scaled sim_c[0] -----------------------------------------
__global__ __launch_bounds__(256) void k_max(const unsigned short* __restrict__ q,
                                             const unsigned short* __restrict__ kb,
                                             unsigned* __restrict__ maxslot) {
  __shared__ unsigned short Ks[80 * 72];
  __shared__ float red[4];
  int tid = threadIdx.x, lane = tid & 63, w = tid >> 6;
  int l15 = lane & 15, qd = lane >> 4;
  int rowbase = blockIdx.x * 128, h = blockIdx.y;
  size_t kbase = (size_t)(1 * 8 + h) * 77 * 64;  // ctx slot 1 = c0
  for (int u = tid; u < 640; u += 256) {
    int r = u >> 3, c8 = (u & 7) * 8;
    u16x8 v = {0, 0, 0, 0, 0, 0, 0, 0};
    if (r < 77) v = *reinterpret_cast<const u16x8*>(&kb[kbase + (size_t)r * 64 + c8]);
    *reinterpret_cast<u16x8*>(&Ks[r * 72 + c8]) = v;
  }
  __syncthreads();
  bf16x8 aq[2][2];
#pragma unroll
  for (int mi = 0; mi < 2; ++mi)
#pragma unroll
    for (int ks = 0; ks < 2; ++ks) {
      int row = rowbase + w * 32 + mi * 16 + l15;
      aq[mi][ks] = *reinterpret_cast<const bf16x8*>(&q[((size_t)(8 + h) * 4096 + row) * 64 + qd * 8 + ks * 32]);
    }
  f32x4 acc[2][5] = {};
#pragma unroll
  for (int jf = 0; jf < 5; ++jf)
#pragma unroll
    for (int ks = 0; ks < 2; ++ks) {
      bf16x8 b = *reinterpret_cast<const bf16x8*>(&Ks[(jf * 16 + l15) * 72 + qd * 8 + ks * 32]);
#pragma unroll
      for (int mi = 0; mi < 2; ++mi)
        acc[mi][jf] = __builtin_amdgcn_mfma_f32_16x16x32_bf16(aq[mi][ks], b, acc[mi][jf], 0, 0, 0);
    }
  float lmax = -3.4e38f;
#pragma unroll
  for (int jf = 0; jf < 5; ++jf) {
    int j = jf * 16 + l15;
    if (j < 77) {
#pragma unroll
      for (int mi = 0; mi < 2; ++mi)
#pragma unroll
        for (int r = 0; r < 4; ++r) lmax = fmaxf(lmax, acc[mi][jf][r] * 0.125f);
    }
  }
  for (int m = 1; m < 64; m <<= 1) lmax = fmaxf(lmax, __shfl_xor(lmax, m, 64));
  if (lane == 0) red[w] = lmax;
  __syncthreads();
  if (tid == 0) {
    float m4 = fmaxf(fmaxf(red[0], red[1]), fmaxf(red[2], red[3]));
    atomicMax(maxslot, enc_f(m4));
  }
}

// --- fused attention: grid (64 rowtiles, 8 h, 2 part) ----------------------
__global__ __launch_bounds__(256) void k_attn(const unsigned short* __restrict__ q,
                                              const unsigned short* __restrict__ kb,
                                              const unsigned short* __restrict__ vt,
                                              const float* __restrict__ extra,
                                              const int* __restrict__ tptr,
                                              const unsigned* __restrict__ maxslot,
                                              unsigned short* __restrict__ att) {
  __shared__ unsigned short Ks[80 * 72];
  __shared__ unsigned short VT[64 * 104];
  __shared__ unsigned short Ps[64 * 104];
  int tid = threadIdx.x, lane = tid & 63, w = tid >> 6;
  int l15 = lane & 15, qd = lane >> 4;
  int rowbase = blockIdx.x * 64, h = blockIdx.y, part = blockIdx.z;
  int bh = part ? 8 + h : h;
  // zero pad cols 80..95 (PV k-range) once
  for (int u = tid; u < 1024; u += 256) {
    int d = u >> 4, j = 80 + (u & 15);
    VT[d * 104 + j] = 0;
    Ps[d * 104 + j] = 0;
  }
  int myrow = rowbase + w * 16 + l15;
  bf16x8 aq[2];
  aq[0] = *reinterpret_cast<const bf16x8*>(&q[((size_t)bh * 4096 + myrow) * 64 + qd * 8]);
  aq[1] = *reinterpret_cast<const bf16x8*>(&q[((size_t)bh * 4096 + myrow) * 64 + qd * 8 + 32]);
  float weight = ((float)(*tptr)) * (4.6f / 50.0f);
  float wmask = weight * dec_f(*maxslot);
  int grow = rowbase + w * 16 + qd * 4;  // +r
  f32x4 oacc[4] = {};
  int nctx = part ? 4 : 1;
  for (int ci = 0; ci < nctx; ++ci) {
    int slot = part ? 1 + ci : 0;
    __syncthreads();  // protect prev-iter LDS reads
    size_t kbase = (size_t)(slot * 8 + h) * 77 * 64;
    size_t vbase = (size_t)(slot * 8 + h) * 64 * 80;
    for (int u = tid; u < 640; u += 256) {
      int r = u >> 3, c8 = (u & 7) * 8;
      u16x8 v = {0, 0, 0, 0, 0, 0, 0, 0};
      if (r < 77) v = *reinterpret_cast<const u16x8*>(&kb[kbase + (size_t)r * 64 + c8]);
      *reinterpret_cast<u16x8*>(&Ks[r * 72 + c8]) = v;
    }
    for (int u = tid; u < 640; u += 256) {
      int d = u / 10, c8 = (u % 10) * 8;
      *reinterpret_cast<u16x8*>(&VT[d * 104 + c8]) =
          *reinterpret_cast<const u16x8*>(&vt[vbase + (size_t)d * 80 + c8]);
    }
    __syncthreads();
    // QK^T
    f32x4 sim[5];
#pragma unroll
    for (int jf = 0; jf < 5; ++jf) {
      bf16x8 b0 = *reinterpret_cast<const bf16x8*>(&Ks[(jf * 16 + l15) * 72 + qd * 8]);
      bf16x8 b1 = *reinterpret_cast<const bf16x8*>(&Ks[(jf * 16 + l15) * 72 + qd * 8 + 32]);
      f32x4 s = {};
      s = __builtin_amdgcn_mfma_f32_16x16x32_bf16(aq[0], b0, s, 0, 0, 0);
      s = __builtin_amdgcn_mfma_f32_16x16x32_bf16(aq[1], b1, s, 0, 0, 0);
      sim[jf] = s;
    }
    // softmax (no max-sub: |logit| <= ~2.5, fp32-safe)
    bool isc0 = (part == 1) && (ci == 0);
    float rowsum[4] = {0.f, 0.f, 0.f, 0.f};
    float e[5][4];
#pragma unroll
    for (int jf = 0; jf < 5; ++jf) {
      int j = jf * 16 + l15;
#pragma unroll
      for (int r = 0; r < 4; ++r) {
        float val = sim[jf][r] * 0.125f;
        float ev = 0.f;
        if (j < 77) {
          if (isc0) val += wmask * extra[((size_t)h * 4096 + grow + r) * 77 + j];
          ev = __expf(val);
        }
        e[jf][r] = ev;
        rowsum[r] += ev;
      }
    }
#pragma unroll
    for (int r = 0; r < 4; ++r) {
      float s = rowsum[r];
      s += __shfl_xor(s, 1, 64); s += __shfl_xor(s, 2, 64);
      s += __shfl_xor(s, 4, 64); s += __shfl_xor(s, 8, 64);
      rowsum[r] = s;
    }
    // store P (bf16) to own rows
#pragma unroll
    for (int jf = 0; jf < 5; ++jf) {
      int j = jf * 16 + l15;
#pragma unroll
      for (int r = 0; r < 4; ++r) Ps[(w * 16 + qd * 4 + r) * 104 + j] = bf_cvt(e[jf][r]);
    }
    // PV (Ps rows are wave-private: no barrier needed; VT covered above)
    bf16x8 pa[3];
#pragma unroll
    for (int ks = 0; ks < 3; ++ks)
      pa[ks] = *reinterpret_cast<const bf16x8*>(&Ps[(w * 16 + l15) * 104 + qd * 8 + ks * 32]);
#pragma unroll
    for (int nf = 0; nf < 4; ++nf) {
      f32x4 o = {};
#pragma unroll
      for (int ks = 0; ks < 3; ++ks) {
        bf16x8 bv = *reinterpret_cast<const bf16x8*>(&VT[(nf * 16 + l15) * 104 + qd * 8 + ks * 32]);
        o = __builtin_amdgcn_mfma_f32_16x16x32_bf16(pa[ks], bv, o, 0, 0, 0);
      }
      if (part == 0) {
#pragma unroll
        for (int r = 0; r < 4; ++r)
          att[((size_t)(grow + r)) * 512 + h * 64 + nf * 16 + l15] = bf_cvt(o[r] / rowsum[r]);
      } else {
#pragma unroll
        for (int r = 0; r < 4; ++r) oacc[nf][r] += o[r] / rowsum[r];
      }
    }
  }
  if (part == 1) {
#pragma unroll
    for (int nf = 0; nf < 4; ++nf)
#pragma unroll
      for (int r = 0; r < 4; ++r)
        att[((size_t)(4096 + grow + r)) * 512 + h * 64 + nf * 16 + l15] = bf_cvt(oacc[nf][r] * 0.25f);
  }
}

// --- out = att @ Wo + bo : M=8192 N=320 K=512 ------------------------------
__global__ __launch_bounds__(256) void k_gemm_out(const unsigned short* __restrict__ att,
                                                  const unsigned short* __restrict__ WoT,
                                                  const float* __restrict__ bo,
                                                  float* __restrict__ out) {
  __shared__ unsigned short As[128 * 40];
  __shared__ unsigned short Bs[64 * 40];
  int tid = threadIdx.x, lane = tid & 63, w = tid >> 6;
  int l15 = lane & 15, qd = lane >> 4;
  int mb = blockIdx.x * 128, nb = blockIdx.y * 64;
  f32x4 acc[2][4] = {};
  for (int k0 = 0; k0 < 512; k0 += 32) {
    for (int u = tid; u < 512; u += 256) {
      int r = u >> 2, c8 = (u & 3) * 8;
      *reinterpret_cast<u16x8*>(&As[r * 40 + c8]) =
          *reinterpret_cast<const u16x8*>(&att[(size_t)(mb + r) * 512 + k0 + c8]);
    }
    for (int u = tid; u < 256; u += 256) {
      int r = u >> 2, c8 = (u & 3) * 8;
      *reinterpret_cast<u16x8*>(&Bs[r * 40 + c8]) =
          *reinterpret_cast<const u16x8*>(&WoT[(size_t)(nb + r) * 512 + k0 + c8]);
    }
    __syncthreads();
    bf16x8 a[2], b[4];
#pragma unroll
    for (int mi = 0; mi < 2; ++mi)
      a[mi] = *reinterpret_cast<const bf16x8*>(&As[(w * 32 + mi * 16 + l15) * 40 + qd * 8]);
#pragma unroll
    for (int nf = 0; nf < 4; ++nf)
      b[nf] = *reinterpret_cast<const bf16x8*>(&Bs[(nf * 16 + l15) * 40 + qd * 8]);
#pragma unroll
    for (int mi = 0; mi < 2; ++mi)
#pragma unroll
      for (int nf = 0; nf < 4; ++nf)
        acc[mi][nf] = __builtin_amdgcn_mfma_f32_16x16x32_bf16(a[mi], b[nf], acc[mi][nf], 0, 0, 0);
    __syncthreads();
  }
#pragma unroll
  for (int mi = 0; mi < 2; ++mi)
#pragma unroll
    for (int nf = 0; nf < 4; ++nf) {
      int n = nb + nf * 16 + l15;
      float bias = bo[n];
#pragma unroll
      for (int r = 0; r < 4; ++r) {
        int m = mb + w * 32 + mi * 16 + qd * 4 + r;
        out[(size_t)m * 320 + n] = acc[mi][nf][r] + bias;
      }
    }
}

extern "C" void kernel_launch(void* const* d_in, const int* in_sizes, int n_in,
                              void* d_out, int out_size, void* d_ws, size_t ws_size,
                              hipStream_t stream) {
  (void)in_sizes; (void)n_in; (void)out_size; (void)ws_size;
  const float* x  = (const float*)d_in[0];
  const float* uc = (const float*)d_in[1];
  const float* ck = (const float*)d_in[2];
  const float* cv = (const float*)d_in[3];
  const float* ex = (const float*)d_in[4];
  const float* Wq = (const float*)d_in[5];
  const float* Wk = (const float*)d_in[6];
  const float* Wv = (const float*)d_in[7];
  const float* Wo = (const float*)d_in[8];
  const float* bo = (const float*)d_in[9];
  const int*   tp = (const int*)d_in[10];

  char* base = (char*)d_ws;
  unsigned short* xb   = (unsigned short*)(base + OFF_XB);
  unsigned short* ctxb = (unsigned short*)(base + OFF_CTXB);
  unsigned short* WqT  = (unsigned short*)(base + OFF_WQT);
  unsigned short* WkT  = (unsigned short*)(base + OFF_WKT);
  unsigned short* WvT  = (unsigned short*)(base + OFF_WVT);
  unsigned short* WoT  = (unsigned short*)(base + OFF_WOT);
  unsigned short* qb   = (unsigned short*)(base + OFF_Q);
  unsigned short* kb   = (unsigned short*)(base + OFF_K);
  unsigned short* vt   = (unsigned short*)(base + OFF_VT);
  unsigned short* att  = (unsigned short*)(base + OFF_ATT);
  unsigned* maxslot    = (unsigned*)(base + OFF_MAX);

  k_convert<<<3080, 256, 0, stream>>>(x, uc, ck, cv, xb, ctxb, maxslot);
  k_tw<<<dim3(16, 24, 4), 256, 0, stream>>>(Wq, Wk, Wv, Wo, WqT, WkT, WvT, WoT);
  k_gemm_q<<<dim3(64, 4), 256, 0, stream>>>(xb, WqT, qb);
  k_gemm_ctx<<<dim3(8, 10), 256, 0, stream>>>(ctxb, WkT, WvT, kb, vt);
  k_max<<<dim3(32, 8), 256, 0, stream>>>(qb, kb, maxslot);
  k_attn<<<dim3(64, 8, 2), 256, 0, stream>>>(qb, kb, vt, ex, tp, maxslot, att);
  k_gemm_out<<<dim3(64, 5), 256, 0, stream>>>(att, WoT, bo, (float*)d_out);
}